// Round 8
// baseline (128.907 us; speedup 1.0000x reference)
//
#include <hip/hip_runtime.h>

#define IN_DIM  3
#define HID_DIM 20
#define OUT_DIM 3
#define N_EXP   5
#define ELEMS   2
#define BLOCK   256
#define SPAN    (BLOCK * ELEMS)   // 512 elements per block

// d_out layout: mixed [B,3] then gate [B,5], fp32.
// R4: dense float4 I/O via LDS, no VGPR clamp -> spill traffic gone.
// R5: packed fp32 pairs (v_pk_fma/v_pk_max), -10us.
// R6 FAILED (+10us): per-iteration LDS weight reads (200 ds_read_b128/thread).
// R7 NEUTRAL: 2x occupancy didn't help -> not occupancy-bound.
// R8: weights preloaded into VGPRs in 10-j-unit chunks via global float2
//   loads with a +threadIdx.y (runtime-0, unprovably-uniform) offset so the
//   compiler cannot scalarize them into the 48-SGPR JIT s_load chain that
//   R5/R7 serialize on. #pragma unroll 1 on the chunk loop bounds register
//   pressure to one 70-VGPR chunk.

typedef float v2f __attribute__((ext_vector_type(2)));

// constant-index component select from a float2 register array
#define F2AT(arr, idx) (((idx) & 1) ? arr[(idx) >> 1].y : arr[(idx) >> 1].x)

__global__ __launch_bounds__(BLOCK) void moe_kernel(
    const float* __restrict__ x,
    const float* __restrict__ W1,   // [E, IN, HID]
    const float* __restrict__ b1,   // [E, HID]
    const float* __restrict__ W2,   // [E, HID, OUT]
    const float* __restrict__ b2,   // [E, OUT]
    const float* __restrict__ Wg,   // [IN, E]
    const float* __restrict__ bg,   // [E]
    float* __restrict__ out,
    int B)
{
    __shared__ float sIO[SPAN * N_EXP];   // 10 KB, reused: x -> gate -> mixed

    const int t = threadIdx.x;
    // Runtime-zero, but the compiler can't prove threadIdx.y==0, so any
    // address containing dz is treated divergent -> load lands in VGPRs.
    const int dz = (int)threadIdx.y;

    const float2* __restrict__ W1f2 = reinterpret_cast<const float2*>(W1);
    const float2* __restrict__ b1f2 = reinterpret_cast<const float2*>(b1);
    const float2* __restrict__ W2f2 = reinterpret_cast<const float2*>(W2);

    const long long blockBase = (long long)blockIdx.x * SPAN;
    float* __restrict__ mixed_out = out;
    float* __restrict__ gate_out  = out + (long long)B * OUT_DIM;

    if (blockBase + SPAN <= (long long)B) {
        const size_t bb = (size_t)blockBase;

        // ---- 1. cooperative dense x load: 384 float4 ----
        {
            const float4* g4 = reinterpret_cast<const float4*>(x + bb * IN_DIM);
            float4* s4 = reinterpret_cast<float4*>(sIO);
            s4[t] = g4[t];
            if (t < (SPAN * IN_DIM) / 4 - BLOCK)            // 128 more
                s4[t + BLOCK] = g4[t + BLOCK];
        }
        __syncthreads();

        // ---- 2. per-thread x: elements 2t,2t+1 = floats 6t..6t+5 (3x b64) --
        v2f xp[IN_DIM];   // xp[i] = (x[2t][i], x[2t+1][i])
        {
            const float2* s2 = reinterpret_cast<const float2*>(sIO);
            float2 a = s2[3 * t + 0];     // x0[0], x0[1]
            float2 b = s2[3 * t + 1];     // x0[2], x1[0]
            float2 c = s2[3 * t + 2];     // x1[1], x1[2]
            xp[0] = (v2f){a.x, b.y};
            xp[1] = (v2f){a.y, c.x};
            xp[2] = (v2f){b.x, c.y};
        }
        __syncthreads();   // all x reads done before sIO is overwritten

        // ---- 3. gate: softmax(x @ Wg + bg), packed pair ----
        v2f gatep[N_EXP];
        {
            v2f lg[N_EXP];
            #pragma unroll
            for (int e = 0; e < N_EXP; ++e) {
                v2f v = (v2f){bg[e], bg[e]};
                #pragma unroll
                for (int i = 0; i < IN_DIM; ++i) {
                    const float w = Wg[i * N_EXP + e];
                    v = __builtin_elementwise_fma(xp[i], (v2f){w, w}, v);
                }
                lg[e] = (v2f){__expf(v.x), __expf(v.y)};
            }
            v2f s = (v2f){0.f, 0.f};
            #pragma unroll
            for (int e = 0; e < N_EXP; ++e) s += lg[e];
            const v2f inv = (v2f){1.0f / s.x, 1.0f / s.y};
            #pragma unroll
            for (int e = 0; e < N_EXP; ++e) gatep[e] = lg[e] * inv;
        }
        // gate -> LDS: 10 floats as 5 aligned float2
        {
            float2* s2 = reinterpret_cast<float2*>(sIO);
            s2[5 * t + 0] = make_float2(gatep[0].x, gatep[1].x);
            s2[5 * t + 1] = make_float2(gatep[2].x, gatep[3].x);
            s2[5 * t + 2] = make_float2(gatep[4].x, gatep[0].y);
            s2[5 * t + 3] = make_float2(gatep[1].y, gatep[2].y);
            s2[5 * t + 4] = make_float2(gatep[3].y, gatep[4].y);
        }
        __syncthreads();

        // ---- 4. cooperative dense gate store: 640 float4 ----
        {
            float4* o4 = reinterpret_cast<float4*>(gate_out + bb * N_EXP);
            const float4* s4 = reinterpret_cast<const float4*>(sIO);
            o4[t] = s4[t];
            o4[t + BLOCK] = s4[t + BLOCK];
            if (t < (SPAN * N_EXP) / 4 - 2 * BLOCK)          // 128 more
                o4[t + 2 * BLOCK] = s4[t + 2 * BLOCK];
        }

        // ---- 5. experts: VGPR-chunked weights, 7 pk-insts per (e,j) ----
        v2f mix[OUT_DIM];
        #pragma unroll
        for (int k = 0; k < OUT_DIM; ++k) mix[k] = (v2f){0.f, 0.f};

        #pragma unroll
        for (int e = 0; e < N_EXP; ++e) {
            v2f oacc[OUT_DIM];
            #pragma unroll
            for (int k = 0; k < OUT_DIM; ++k) {
                const float bk = b2[e * OUT_DIM + k];   // uniform, tiny
                oacc[k] = (v2f){bk, bk};
            }
            #pragma unroll 1   // bound live pressure to one 70-VGPR chunk
            for (int jt = 0; jt < 2; ++jt) {
                const int h0 = jt * 5;   // float2 offset within a 10-f2 row
                // ---- preload 35 float2 (70 floats) into VGPRs ----
                float2 w1r0[5], w1r1[5], w1r2[5], b1r[5], w2r[15];
                #pragma unroll
                for (int q = 0; q < 5; ++q) {
                    w1r0[q] = W1f2[(e * IN_DIM + 0) * 10 + h0 + q + dz];
                    w1r1[q] = W1f2[(e * IN_DIM + 1) * 10 + h0 + q + dz];
                    w1r2[q] = W1f2[(e * IN_DIM + 2) * 10 + h0 + q + dz];
                    b1r[q]  = b1f2[e * 10 + h0 + q + dz];
                }
                #pragma unroll
                for (int q = 0; q < 15; ++q)
                    w2r[q] = W2f2[e * 30 + 3 * h0 + q + dz];
                // ---- 10 hidden units from registers, stall-free ----
                #pragma unroll
                for (int jj = 0; jj < 10; ++jj) {
                    const float w10 = F2AT(w1r0, jj);
                    const float w11 = F2AT(w1r1, jj);
                    const float w12 = F2AT(w1r2, jj);
                    const float bb1 = F2AT(b1r, jj);
                    const float w20 = F2AT(w2r, 3 * jj + 0);
                    const float w21 = F2AT(w2r, 3 * jj + 1);
                    const float w22 = F2AT(w2r, 3 * jj + 2);
                    v2f h = __builtin_elementwise_fma(xp[2], (v2f){w12, w12},
                            __builtin_elementwise_fma(xp[1], (v2f){w11, w11},
                            __builtin_elementwise_fma(xp[0], (v2f){w10, w10},
                                                      (v2f){bb1, bb1})));
                    h = __builtin_elementwise_max(h, (v2f){0.f, 0.f});
                    oacc[0] = __builtin_elementwise_fma(h, (v2f){w20, w20}, oacc[0]);
                    oacc[1] = __builtin_elementwise_fma(h, (v2f){w21, w21}, oacc[1]);
                    oacc[2] = __builtin_elementwise_fma(h, (v2f){w22, w22}, oacc[2]);
                }
            }
            #pragma unroll
            for (int k = 0; k < OUT_DIM; ++k)
                mix[k] = __builtin_elementwise_fma(gatep[e], oacc[k], mix[k]);
        }
        __syncthreads();   // step-4 LDS reads retired before overwrite

        // ---- 6. mixed -> LDS: 6 floats as 3 aligned float2 ----
        {
            float2* s2 = reinterpret_cast<float2*>(sIO);
            s2[3 * t + 0] = make_float2(mix[0].x, mix[1].x);
            s2[3 * t + 1] = make_float2(mix[2].x, mix[0].y);
            s2[3 * t + 2] = make_float2(mix[1].y, mix[2].y);
        }
        __syncthreads();

        // ---- 7. cooperative dense mixed store: 384 float4 ----
        {
            float4* o4 = reinterpret_cast<float4*>(mixed_out + bb * OUT_DIM);
            const float4* s4 = reinterpret_cast<const float4*>(sIO);
            o4[t] = s4[t];
            if (t < (SPAN * OUT_DIM) / 4 - BLOCK)            // 128 more
                o4[t + BLOCK] = s4[t + BLOCK];
        }
    } else {
        // ---- guarded tail (never taken at B = 1M): per-element scalar ----
        for (int c = 0; c < ELEMS; ++c) {
            const long long bidx = blockBase + (long long)c * BLOCK + t;
            if (bidx >= (long long)B) continue;
            float xv[IN_DIM];
            for (int i = 0; i < IN_DIM; ++i) xv[i] = x[bidx * IN_DIM + i];

            float lg[N_EXP]; float s = 0.f;
            for (int e = 0; e < N_EXP; ++e) {
                float v = bg[e];
                for (int i = 0; i < IN_DIM; ++i)
                    v = fmaf(xv[i], Wg[i * N_EXP + e], v);
                v = __expf(v); lg[e] = v; s += v;
            }
            const float inv = 1.0f / s;
            for (int e = 0; e < N_EXP; ++e) lg[e] *= inv;

            float mixv[OUT_DIM] = {0.f, 0.f, 0.f};
            for (int e = 0; e < N_EXP; ++e) {
                for (int k = 0; k < OUT_DIM; ++k)
                    mixv[k] = fmaf(lg[e], b2[e * OUT_DIM + k], mixv[k]);
                for (int j = 0; j < HID_DIM; ++j) {
                    float h = b1[e * HID_DIM + j];
                    for (int i = 0; i < IN_DIM; ++i)
                        h = fmaf(xv[i], W1[(e * IN_DIM + i) * HID_DIM + j], h);
                    h = fmaxf(h, 0.f);
                    const float hg = h * lg[e];
                    for (int k = 0; k < OUT_DIM; ++k)
                        mixv[k] = fmaf(hg, W2[(e * HID_DIM + j) * OUT_DIM + k], mixv[k]);
                }
            }
            for (int k = 0; k < OUT_DIM; ++k)
                mixed_out[bidx * OUT_DIM + k] = mixv[k];
            for (int e = 0; e < N_EXP; ++e)
                gate_out[bidx * N_EXP + e] = lg[e];
        }
    }
}

extern "C" void kernel_launch(void* const* d_in, const int* in_sizes, int n_in,
                              void* d_out, int out_size, void* d_ws, size_t ws_size,
                              hipStream_t stream) {
    const float* x  = (const float*)d_in[0];
    const float* W1 = (const float*)d_in[1];
    const float* b1 = (const float*)d_in[2];
    const float* W2 = (const float*)d_in[3];
    const float* b2 = (const float*)d_in[4];
    const float* Wg = (const float*)d_in[5];
    const float* bg = (const float*)d_in[6];
    float* out = (float*)d_out;

    const int B = in_sizes[0] / IN_DIM;
    const int grid = (B + SPAN - 1) / SPAN;

    moe_kernel<<<grid, BLOCK, 0, stream>>>(x, W1, b1, W2, b2, Wg, bg, out, B);
}

// Round 9
// 99.807 us; speedup vs baseline: 1.2916x; 1.2916x over previous
//
#include <hip/hip_runtime.h>

#define IN_DIM  3
#define HID_DIM 20
#define OUT_DIM 3
#define N_EXP   5
#define ELEMS   8
#define PAIRS   (ELEMS / 2)
#define BLOCK   256
#define SPAN    (BLOCK * ELEMS)   // 2048 elements per block

// d_out layout: mixed [B,3] then gate [B,5], fp32.
// Ladder: R4 dense LDS-staged I/O (ideal 40MB traffic, proven by R8 counters);
// R5 packed fp32 pairs; R6 LDS weights FAILED (+10us); R7 2x occupancy
// NEUTRAL; R8 VMEM weights FAILED (+28us, but gave counters: all pipes idle
// -> per-wave fixed-cost bound). R9: amortize the per-wave fixed cost (735
// s_load weight chain + I/O latency) over 4x elements: ELEMS=8, grid=512 =
// exactly 2 blocks/CU. launch_bounds(256,2) -> VGPR cap 256 (live ~150-190,
// no 128-clamp spill like R3, no 256-clamp spill like R1).

typedef float v2f __attribute__((ext_vector_type(2)));

__global__ __launch_bounds__(BLOCK, 2) void moe_kernel(
    const float* __restrict__ x,
    const float* __restrict__ W1,   // [E, IN, HID]
    const float* __restrict__ b1,   // [E, HID]
    const float* __restrict__ W2,   // [E, HID, OUT]
    const float* __restrict__ b2,   // [E, OUT]
    const float* __restrict__ Wg,   // [IN, E]
    const float* __restrict__ bg,   // [E]
    float* __restrict__ out,
    int B)
{
    __shared__ float sIO[SPAN * N_EXP];   // 40 KB, reused: x -> gate -> mixed

    const int t = threadIdx.x;
    const long long blockBase = (long long)blockIdx.x * SPAN;
    float* __restrict__ mixed_out = out;
    float* __restrict__ gate_out  = out + (long long)B * OUT_DIM;

    if (blockBase + SPAN <= (long long)B) {
        const size_t bb = (size_t)blockBase;

        // ---- 1. cooperative dense x load: 1536 float4 ----
        {
            const float4* g4 = reinterpret_cast<const float4*>(x + bb * IN_DIM);
            float4* s4 = reinterpret_cast<float4*>(sIO);
            #pragma unroll
            for (int k = 0; k < (SPAN * IN_DIM) / (4 * BLOCK); ++k)   // 6
                s4[t + k * BLOCK] = g4[t + k * BLOCK];
        }
        __syncthreads();

        // ---- 2. per-thread x: elements 8t..8t+7 -> 4 packed pairs ----
        v2f xp[PAIRS][IN_DIM];   // xp[p][i] = (x[8t+2p][i], x[8t+2p+1][i])
        {
            const float4* s4 = reinterpret_cast<const float4*>(sIO);
            float f[ELEMS * IN_DIM];
            #pragma unroll
            for (int k = 0; k < 6; ++k) {
                float4 v = s4[6 * t + k];
                f[4 * k + 0] = v.x; f[4 * k + 1] = v.y;
                f[4 * k + 2] = v.z; f[4 * k + 3] = v.w;
            }
            #pragma unroll
            for (int p = 0; p < PAIRS; ++p)
                #pragma unroll
                for (int i = 0; i < IN_DIM; ++i)
                    xp[p][i] = (v2f){f[(2 * p) * IN_DIM + i],
                                     f[(2 * p + 1) * IN_DIM + i]};
        }
        __syncthreads();   // all x reads done before sIO is overwritten

        // ---- 3. gate: softmax(x @ Wg + bg), packed pairs ----
        v2f gatep[PAIRS][N_EXP];
        #pragma unroll
        for (int p = 0; p < PAIRS; ++p) {
            v2f lg[N_EXP];
            #pragma unroll
            for (int e = 0; e < N_EXP; ++e) {
                v2f v = (v2f){bg[e], bg[e]};
                #pragma unroll
                for (int i = 0; i < IN_DIM; ++i) {
                    const float w = Wg[i * N_EXP + e];
                    v = __builtin_elementwise_fma(xp[p][i], (v2f){w, w}, v);
                }
                lg[e] = (v2f){__expf(v.x), __expf(v.y)};
            }
            v2f s = (v2f){0.f, 0.f};
            #pragma unroll
            for (int e = 0; e < N_EXP; ++e) s += lg[e];
            const v2f inv = (v2f){1.0f / s.x, 1.0f / s.y};
            #pragma unroll
            for (int e = 0; e < N_EXP; ++e) gatep[p][e] = lg[e] * inv;
        }
        // gate -> LDS: 40 floats as 10 aligned float4 per thread
        {
            float4* s4 = reinterpret_cast<float4*>(sIO);
            float g[ELEMS * N_EXP];
            #pragma unroll
            for (int p = 0; p < PAIRS; ++p)
                #pragma unroll
                for (int e = 0; e < N_EXP; ++e) {
                    g[(2 * p) * N_EXP + e]     = gatep[p][e].x;
                    g[(2 * p + 1) * N_EXP + e] = gatep[p][e].y;
                }
            #pragma unroll
            for (int k = 0; k < 10; ++k)
                s4[10 * t + k] = make_float4(g[4 * k + 0], g[4 * k + 1],
                                             g[4 * k + 2], g[4 * k + 3]);
        }
        __syncthreads();

        // ---- 4. cooperative dense gate store: 2560 float4 ----
        {
            float4* o4 = reinterpret_cast<float4*>(gate_out + bb * N_EXP);
            const float4* s4 = reinterpret_cast<const float4*>(sIO);
            #pragma unroll
            for (int k = 0; k < (SPAN * N_EXP) / (4 * BLOCK); ++k)    // 10
                o4[t + k * BLOCK] = s4[t + k * BLOCK];
        }

        // ---- 5. experts: SMEM-uniform weights, 7 pk-insts/(e,j)/pair ----
        v2f mix[PAIRS][OUT_DIM];
        #pragma unroll
        for (int p = 0; p < PAIRS; ++p)
            #pragma unroll
            for (int k = 0; k < OUT_DIM; ++k) mix[p][k] = (v2f){0.f, 0.f};

        #pragma unroll
        for (int e = 0; e < N_EXP; ++e) {
            v2f oacc[PAIRS][OUT_DIM];
            #pragma unroll
            for (int p = 0; p < PAIRS; ++p)
                #pragma unroll
                for (int k = 0; k < OUT_DIM; ++k) {
                    const float bk = b2[e * OUT_DIM + k];
                    oacc[p][k] = (v2f){bk, bk};
                }
            #pragma unroll
            for (int j = 0; j < HID_DIM; ++j) {
                // 7 wave-uniform weight loads (scalar cache / SGPR broadcast)
                const float w10 = W1[(e * IN_DIM + 0) * HID_DIM + j];
                const float w11 = W1[(e * IN_DIM + 1) * HID_DIM + j];
                const float w12 = W1[(e * IN_DIM + 2) * HID_DIM + j];
                const float bb1 = b1[e * HID_DIM + j];
                const float w20 = W2[(e * HID_DIM + j) * OUT_DIM + 0];
                const float w21 = W2[(e * HID_DIM + j) * OUT_DIM + 1];
                const float w22 = W2[(e * HID_DIM + j) * OUT_DIM + 2];
                #pragma unroll
                for (int p = 0; p < PAIRS; ++p) {
                    v2f h = __builtin_elementwise_fma(xp[p][2], (v2f){w12, w12},
                            __builtin_elementwise_fma(xp[p][1], (v2f){w11, w11},
                            __builtin_elementwise_fma(xp[p][0], (v2f){w10, w10},
                                                      (v2f){bb1, bb1})));
                    h = __builtin_elementwise_max(h, (v2f){0.f, 0.f});
                    oacc[p][0] = __builtin_elementwise_fma(h, (v2f){w20, w20}, oacc[p][0]);
                    oacc[p][1] = __builtin_elementwise_fma(h, (v2f){w21, w21}, oacc[p][1]);
                    oacc[p][2] = __builtin_elementwise_fma(h, (v2f){w22, w22}, oacc[p][2]);
                }
            }
            #pragma unroll
            for (int p = 0; p < PAIRS; ++p)
                #pragma unroll
                for (int k = 0; k < OUT_DIM; ++k)
                    mix[p][k] = __builtin_elementwise_fma(gatep[p][e], oacc[p][k],
                                                          mix[p][k]);
        }
        __syncthreads();   // step-4 LDS reads retired before overwrite

        // ---- 6. mixed -> LDS: 24 floats as 6 aligned float4 ----
        {
            float4* s4 = reinterpret_cast<float4*>(sIO);
            float m[ELEMS * OUT_DIM];
            #pragma unroll
            for (int p = 0; p < PAIRS; ++p)
                #pragma unroll
                for (int k = 0; k < OUT_DIM; ++k) {
                    m[(2 * p) * OUT_DIM + k]     = mix[p][k].x;
                    m[(2 * p + 1) * OUT_DIM + k] = mix[p][k].y;
                }
            #pragma unroll
            for (int k = 0; k < 6; ++k)
                s4[6 * t + k] = make_float4(m[4 * k + 0], m[4 * k + 1],
                                            m[4 * k + 2], m[4 * k + 3]);
        }
        __syncthreads();

        // ---- 7. cooperative dense mixed store: 1536 float4 ----
        {
            float4* o4 = reinterpret_cast<float4*>(mixed_out + bb * OUT_DIM);
            const float4* s4 = reinterpret_cast<const float4*>(sIO);
            #pragma unroll
            for (int k = 0; k < (SPAN * OUT_DIM) / (4 * BLOCK); ++k)  // 6
                o4[t + k * BLOCK] = s4[t + k * BLOCK];
        }
    } else {
        // ---- guarded tail (never taken at B = 1M): per-element scalar ----
        for (int c = 0; c < ELEMS; ++c) {
            const long long bidx = blockBase + (long long)c * BLOCK + t;
            if (bidx >= (long long)B) continue;
            float xv[IN_DIM];
            for (int i = 0; i < IN_DIM; ++i) xv[i] = x[bidx * IN_DIM + i];

            float lg[N_EXP]; float s = 0.f;
            for (int e = 0; e < N_EXP; ++e) {
                float v = bg[e];
                for (int i = 0; i < IN_DIM; ++i)
                    v = fmaf(xv[i], Wg[i * N_EXP + e], v);
                v = __expf(v); lg[e] = v; s += v;
            }
            const float inv = 1.0f / s;
            for (int e = 0; e < N_EXP; ++e) lg[e] *= inv;

            float mixv[OUT_DIM] = {0.f, 0.f, 0.f};
            for (int e = 0; e < N_EXP; ++e) {
                for (int k = 0; k < OUT_DIM; ++k)
                    mixv[k] = fmaf(lg[e], b2[e * OUT_DIM + k], mixv[k]);
                for (int j = 0; j < HID_DIM; ++j) {
                    float h = b1[e * HID_DIM + j];
                    for (int i = 0; i < IN_DIM; ++i)
                        h = fmaf(xv[i], W1[(e * IN_DIM + i) * HID_DIM + j], h);
                    h = fmaxf(h, 0.f);
                    const float hg = h * lg[e];
                    for (int k = 0; k < OUT_DIM; ++k)
                        mixv[k] = fmaf(hg, W2[(e * HID_DIM + j) * OUT_DIM + k], mixv[k]);
                }
            }
            for (int k = 0; k < OUT_DIM; ++k)
                mixed_out[bidx * OUT_DIM + k] = mixv[k];
            for (int e = 0; e < N_EXP; ++e)
                gate_out[bidx * N_EXP + e] = lg[e];
        }
    }
}

extern "C" void kernel_launch(void* const* d_in, const int* in_sizes, int n_in,
                              void* d_out, int out_size, void* d_ws, size_t ws_size,
                              hipStream_t stream) {
    const float* x  = (const float*)d_in[0];
    const float* W1 = (const float*)d_in[1];
    const float* b1 = (const float*)d_in[2];
    const float* W2 = (const float*)d_in[3];
    const float* b2 = (const float*)d_in[4];
    const float* Wg = (const float*)d_in[5];
    const float* bg = (const float*)d_in[6];
    float* out = (float*)d_out;

    const int B = in_sizes[0] / IN_DIM;
    const int grid = (B + SPAN - 1) / SPAN;

    moe_kernel<<<grid, BLOCK, 0, stream>>>(x, W1, b1, W2, b2, Wg, bg, out, B);
}

// Round 10
// 95.869 us; speedup vs baseline: 1.3446x; 1.0411x over previous
//
#include <hip/hip_runtime.h>

#define IN_DIM  3
#define HID_DIM 20
#define OUT_DIM 3
#define N_EXP   5
#define BLOCK   256

// d_out layout: mixed [B,3] then gate [B,5], fp32.
// Ladder: R4 LDS-staged dense I/O; R5 packed fp32 pairs; R6 LDS weights
// FAILED; R7/R9 wave-count & per-wave-amortization NEUTRAL (time scales with
// total elements, all pipes idle); R8 VMEM weights FAILED but proved traffic
// is ideal (40MB) and exonerated spill-free strided access (R2's 2.4GB was
// spills, not stride). R10: remove the 5-barrier LDS staging skeleton
// entirely — barrier-free, one thread = one element pair, small-stride
// (24/40B) direct global I/O whose partial lines complete within 3-5
// back-to-back instructions (L2 merge window). Weights stay SMEM-uniform.

typedef float v2f __attribute__((ext_vector_type(2)));

__global__ __launch_bounds__(BLOCK) void moe_kernel(
    const float* __restrict__ x,
    const float* __restrict__ W1,   // [E, IN, HID]
    const float* __restrict__ b1,   // [E, HID]
    const float* __restrict__ W2,   // [E, HID, OUT]
    const float* __restrict__ b2,   // [E, OUT]
    const float* __restrict__ Wg,   // [IN, E]
    const float* __restrict__ bg,   // [E]
    float* __restrict__ out,
    int B)
{
    const long long g = (long long)blockIdx.x * BLOCK + threadIdx.x;  // pair id
    float* __restrict__ mixed_out = out;
    float* __restrict__ gate_out  = out + (long long)B * OUT_DIM;

    if (2 * g + 1 < (long long)B) {
        // ---- 1. x loads: 3 float2 at 24B lane stride (dense wave span) ----
        v2f xp[IN_DIM];   // xp[i] = (x[2g][i], x[2g+1][i])
        {
            const float2* x2 = reinterpret_cast<const float2*>(x + 6 * g);
            float2 a = x2[0];   // x0[0], x0[1]
            float2 b = x2[1];   // x0[2], x1[0]
            float2 c = x2[2];   // x1[1], x1[2]
            xp[0] = (v2f){a.x, b.y};
            xp[1] = (v2f){a.y, c.x};
            xp[2] = (v2f){b.x, c.y};
        }

        // ---- 2. gate: softmax(x @ Wg + bg), packed pair ----
        v2f gatep[N_EXP];
        {
            v2f lg[N_EXP];
            #pragma unroll
            for (int e = 0; e < N_EXP; ++e) {
                v2f v = (v2f){bg[e], bg[e]};
                #pragma unroll
                for (int i = 0; i < IN_DIM; ++i) {
                    const float w = Wg[i * N_EXP + e];
                    v = __builtin_elementwise_fma(xp[i], (v2f){w, w}, v);
                }
                lg[e] = (v2f){__expf(v.x), __expf(v.y)};
            }
            v2f s = (v2f){0.f, 0.f};
            #pragma unroll
            for (int e = 0; e < N_EXP; ++e) s += lg[e];
            const v2f inv = (v2f){1.0f / s.x, 1.0f / s.y};
            #pragma unroll
            for (int e = 0; e < N_EXP; ++e) gatep[e] = lg[e] * inv;
        }

        // ---- 3. gate stores: 5 float2 at 40B lane stride (dense span) ----
        {
            float2* g2 = reinterpret_cast<float2*>(gate_out + 10 * g);
            g2[0] = make_float2(gatep[0].x, gatep[1].x);
            g2[1] = make_float2(gatep[2].x, gatep[3].x);
            g2[2] = make_float2(gatep[4].x, gatep[0].y);
            g2[3] = make_float2(gatep[1].y, gatep[2].y);
            g2[4] = make_float2(gatep[3].y, gatep[4].y);
        }

        // ---- 4. experts: SMEM-uniform weights, 7 pk-insts per (e,j) ----
        v2f mix[OUT_DIM];
        #pragma unroll
        for (int k = 0; k < OUT_DIM; ++k) mix[k] = (v2f){0.f, 0.f};

        #pragma unroll
        for (int e = 0; e < N_EXP; ++e) {
            v2f oacc[OUT_DIM];
            #pragma unroll
            for (int k = 0; k < OUT_DIM; ++k) {
                const float bk = b2[e * OUT_DIM + k];
                oacc[k] = (v2f){bk, bk};
            }
            #pragma unroll
            for (int j = 0; j < HID_DIM; ++j) {
                const float w10 = W1[(e * IN_DIM + 0) * HID_DIM + j];
                const float w11 = W1[(e * IN_DIM + 1) * HID_DIM + j];
                const float w12 = W1[(e * IN_DIM + 2) * HID_DIM + j];
                const float bb1 = b1[e * HID_DIM + j];
                const float w20 = W2[(e * HID_DIM + j) * OUT_DIM + 0];
                const float w21 = W2[(e * HID_DIM + j) * OUT_DIM + 1];
                const float w22 = W2[(e * HID_DIM + j) * OUT_DIM + 2];
                v2f h = __builtin_elementwise_fma(xp[2], (v2f){w12, w12},
                        __builtin_elementwise_fma(xp[1], (v2f){w11, w11},
                        __builtin_elementwise_fma(xp[0], (v2f){w10, w10},
                                                  (v2f){bb1, bb1})));
                h = __builtin_elementwise_max(h, (v2f){0.f, 0.f});
                oacc[0] = __builtin_elementwise_fma(h, (v2f){w20, w20}, oacc[0]);
                oacc[1] = __builtin_elementwise_fma(h, (v2f){w21, w21}, oacc[1]);
                oacc[2] = __builtin_elementwise_fma(h, (v2f){w22, w22}, oacc[2]);
            }
            #pragma unroll
            for (int k = 0; k < OUT_DIM; ++k)
                mix[k] = __builtin_elementwise_fma(gatep[e], oacc[k], mix[k]);
        }

        // ---- 5. mixed stores: 3 float2 at 24B lane stride (dense span) ----
        {
            float2* m2 = reinterpret_cast<float2*>(mixed_out + 6 * g);
            m2[0] = make_float2(mix[0].x, mix[1].x);
            m2[1] = make_float2(mix[2].x, mix[0].y);
            m2[2] = make_float2(mix[1].y, mix[2].y);
        }
    } else if (2 * g < (long long)B) {
        // ---- odd-B tail: single scalar element ----
        const long long bidx = 2 * g;
        float xv[IN_DIM];
        for (int i = 0; i < IN_DIM; ++i) xv[i] = x[bidx * IN_DIM + i];

        float lg[N_EXP]; float s = 0.f;
        for (int e = 0; e < N_EXP; ++e) {
            float v = bg[e];
            for (int i = 0; i < IN_DIM; ++i)
                v = fmaf(xv[i], Wg[i * N_EXP + e], v);
            v = __expf(v); lg[e] = v; s += v;
        }
        const float inv = 1.0f / s;
        for (int e = 0; e < N_EXP; ++e) lg[e] *= inv;

        float mixv[OUT_DIM] = {0.f, 0.f, 0.f};
        for (int e = 0; e < N_EXP; ++e) {
            for (int k = 0; k < OUT_DIM; ++k)
                mixv[k] = fmaf(lg[e], b2[e * OUT_DIM + k], mixv[k]);
            for (int j = 0; j < HID_DIM; ++j) {
                float h = b1[e * HID_DIM + j];
                for (int i = 0; i < IN_DIM; ++i)
                    h = fmaf(xv[i], W1[(e * IN_DIM + i) * HID_DIM + j], h);
                h = fmaxf(h, 0.f);
                const float hg = h * lg[e];
                for (int k = 0; k < OUT_DIM; ++k)
                    mixv[k] = fmaf(hg, W2[(e * HID_DIM + j) * OUT_DIM + k], mixv[k]);
            }
        }
        for (int k = 0; k < OUT_DIM; ++k)
            mixed_out[bidx * OUT_DIM + k] = mixv[k];
        for (int e = 0; e < N_EXP; ++e)
            gate_out[bidx * N_EXP + e] = lg[e];
    }
}

extern "C" void kernel_launch(void* const* d_in, const int* in_sizes, int n_in,
                              void* d_out, int out_size, void* d_ws, size_t ws_size,
                              hipStream_t stream) {
    const float* x  = (const float*)d_in[0];
    const float* W1 = (const float*)d_in[1];
    const float* b1 = (const float*)d_in[2];
    const float* W2 = (const float*)d_in[3];
    const float* b2 = (const float*)d_in[4];
    const float* Wg = (const float*)d_in[5];
    const float* bg = (const float*)d_in[6];
    float* out = (float*)d_out;

    const int B = in_sizes[0] / IN_DIM;
    const long long pairs = ((long long)B + 1) / 2;
    const int grid = (int)((pairs + BLOCK - 1) / BLOCK);

    moe_kernel<<<grid, BLOCK, 0, stream>>>(x, W1, b1, W2, b2, Wg, bg, out, B);
}